// Round 3
// baseline (603.891 us; speedup 1.0000x reference)
//
#include <hip/hip_runtime.h>
#include <math.h>

typedef unsigned short u16;
typedef unsigned short u16x8 __attribute__((ext_vector_type(8)));
typedef _Float16 f16x8 __attribute__((ext_vector_type(8)));
typedef float f32x4 __attribute__((ext_vector_type(4)));

#define LOG2E 1.4426950408889634f

__device__ __forceinline__ u16 f2h(float f) {
    return __builtin_bit_cast(u16, (_Float16)f);
}
__device__ __forceinline__ float h2f(u16 u) {
    return (float)__builtin_bit_cast(_Float16, u);
}

// load 8 consecutive elements as f16-bits (converting from fp32 if needed)
template <typename T> __device__ __forceinline__ u16x8 ld8(const T* p);
template <> __device__ __forceinline__ u16x8 ld8<u16>(const u16* p) {
    return *(const u16x8*)p;   // already f16 bits
}
template <> __device__ __forceinline__ u16x8 ld8<float>(const float* p) {
    f32x4 a = *(const f32x4*)p;
    f32x4 b = *(const f32x4*)(p + 4);
    u16x8 r;
    r[0] = f2h(a[0]); r[1] = f2h(a[1]); r[2] = f2h(a[2]); r[3] = f2h(a[3]);
    r[4] = f2h(b[0]); r[5] = f2h(b[1]); r[6] = f2h(b[2]); r[7] = f2h(b[3]);
    return r;
}

// ---------------------------------------------------------------------------
// GEMM: C[M,N] = A[M,K] @ W[N,K]^T + bias   (f16 MFMA, fp32 accum)
// TIN: dtype of A (float or f16-as-u16). W/bias fp32 (converted on stage).
// TOUT: u16 (f16) or float. 128x128 tile, BK=32, 4 waves 2x2 of 64x64.
// LDS pitch 40 (=32+8): frag reads land 2-way on banks (free, m136).
// ---------------------------------------------------------------------------
template <typename TIN, typename TOUT>
__global__ __launch_bounds__(256) void gemm_bt(
    const TIN* __restrict__ A,
    const float* __restrict__ W0, const float* __restrict__ W1, const float* __restrict__ W2,
    const float* __restrict__ B0, const float* __restrict__ B1, const float* __restrict__ B2,
    TOUT* __restrict__ Cb, int M, int N, int K)
{
    const int z = blockIdx.z;
    const float* W    = (z == 0) ? W0 : ((z == 1) ? W1 : W2);
    const float* bias = (z == 0) ? B0 : ((z == 1) ? B1 : B2);
    TOUT* C = Cb + (size_t)z * (size_t)M * (size_t)N;

    const int m0 = blockIdx.y * 128;
    const int n0 = blockIdx.x * 128;

    __shared__ __attribute__((aligned(16))) u16 As[128 * 40];
    __shared__ __attribute__((aligned(16))) u16 Bs[128 * 40];

    const int tid  = threadIdx.x;
    const int l    = tid & 63;
    const int wv   = tid >> 6;
    const int wm   = (wv >> 1) * 64;
    const int wn   = (wv & 1) * 64;
    const int quad = l >> 4;
    const int lan  = l & 15;

    // staging: 512 chunks of 8 elems per matrix, 2 per thread
    const int c0 = tid, c1 = tid + 256;
    const int r0 = c0 >> 2, k0c = (c0 & 3) * 8;
    const int r1 = c1 >> 2, k1c = (c1 & 3) * 8;
    const TIN*   pA0 = A + (size_t)(m0 + r0) * K + k0c;
    const TIN*   pA1 = A + (size_t)(m0 + r1) * K + k1c;
    const float* pB0 = W + (size_t)(n0 + r0) * K + k0c;
    const float* pB1 = W + (size_t)(n0 + r1) * K + k1c;

    f32x4 acc[4][4] = {};

    for (int kt = 0; kt < K; kt += 32) {
        u16x8 a0 = ld8(pA0 + kt);
        u16x8 a1 = ld8(pA1 + kt);
        u16x8 b0 = ld8(pB0 + kt);
        u16x8 b1 = ld8(pB1 + kt);
        __syncthreads();
        *(u16x8*)(&As[r0 * 40 + k0c]) = a0;
        *(u16x8*)(&As[r1 * 40 + k1c]) = a1;
        *(u16x8*)(&Bs[r0 * 40 + k0c]) = b0;
        *(u16x8*)(&Bs[r1 * 40 + k1c]) = b1;
        __syncthreads();

        f16x8 af[4], bfr[4];
#pragma unroll
        for (int i = 0; i < 4; i++)
            af[i] = __builtin_bit_cast(f16x8, *(const u16x8*)(&As[(wm + i * 16 + lan) * 40 + quad * 8]));
#pragma unroll
        for (int j = 0; j < 4; j++)
            bfr[j] = __builtin_bit_cast(f16x8, *(const u16x8*)(&Bs[(wn + j * 16 + lan) * 40 + quad * 8]));
#pragma unroll
        for (int i = 0; i < 4; i++)
#pragma unroll
            for (int j = 0; j < 4; j++)
                acc[i][j] = __builtin_amdgcn_mfma_f32_16x16x32_f16(af[i], bfr[j], acc[i][j], 0, 0, 0);
    }

    // epilogue: C/D layout row=(lane>>4)*4+r, col=lane&15  (m89/m91 verified)
#pragma unroll
    for (int j = 0; j < 4; j++) {
        const int col = n0 + wn + j * 16 + lan;
        const float bj = bias[col];
#pragma unroll
        for (int i = 0; i < 4; i++) {
#pragma unroll
            for (int r = 0; r < 4; r++) {
                const int row = m0 + wm + i * 16 + quad * 4 + r;
                const float v = acc[i][j][r] + bj;
                if constexpr (sizeof(TOUT) == 2)
                    C[(size_t)row * N + col] = f2h(v);
                else
                    C[(size_t)row * N + col] = v;
            }
        }
    }
}

// ---------------------------------------------------------------------------
// RMSNorm (inner=2048) + RoPE (transposed variant) + history key scale.
// One block per (b,s) row; in-place on f16 q/k. q pre-scaled by 1/sqrt(128).
// ---------------------------------------------------------------------------
__global__ __launch_bounds__(256) void norm_rope(
    u16* __restrict__ q, u16* __restrict__ k,
    const float* __restrict__ rot,
    const float* __restrict__ nqw, const float* __restrict__ nkw,
    const float* __restrict__ hks, const int* __restrict__ oclp)
{
    const int row = blockIdx.x;       // 0..4095 (b*2048 + s)
    const int s = row & 2047;
    const int t = threadIdx.x;
    const size_t base = (size_t)row * 2048 + t * 8;

    u16x8 q8 = *(const u16x8*)(q + base);
    u16x8 k8 = *(const u16x8*)(k + base);

    float qf[8], kf[8];
    float sq = 0.f, sk = 0.f;
#pragma unroll
    for (int i = 0; i < 8; i++) {
        qf[i] = h2f(q8[i]); sq += qf[i] * qf[i];
        kf[i] = h2f(k8[i]); sk += kf[i] * kf[i];
    }
#pragma unroll
    for (int off = 32; off > 0; off >>= 1) {
        sq += __shfl_down(sq, off);
        sk += __shfl_down(sk, off);
    }
    __shared__ float rq[4], rk[4];
    const int wv = t >> 6;
    if ((t & 63) == 0) { rq[wv] = sq; rk[wv] = sk; }
    __syncthreads();
    const float tq = rq[0] + rq[1] + rq[2] + rq[3];
    const float tk = rk[0] + rk[1] + rk[2] + rk[3];
    const float scq = rsqrtf(tq * (1.0f / 2048.0f) + 1e-5f);
    const float sck = rsqrtf(tk * (1.0f / 2048.0f) + 1e-5f);
#pragma unroll
    for (int i = 0; i < 8; i++) {
        qf[i] *= scq * nqw[t * 8 + i];
        kf[i] *= sck * nkw[t * 8 + i];
    }
    // rope pairs (2i,2i+1) within head; cos_i = rot[s][2i], sin_i = rot[s][128+2i+1]
    const int e0  = t * 8;
    const int dh0 = e0 & 127;
    const int h   = e0 >> 7;
    float qo[8], ko[8];
#pragma unroll
    for (int p = 0; p < 4; p++) {
        const int dh = dh0 + 2 * p;
        const float c  = rot[s * 256 + dh];
        const float sn = rot[s * 256 + 128 + dh + 1];
        qo[2 * p]     = qf[2 * p] * c  - qf[2 * p + 1] * sn;
        qo[2 * p + 1] = qf[2 * p] * sn + qf[2 * p + 1] * c;
        ko[2 * p]     = kf[2 * p] * c  - kf[2 * p + 1] * sn;
        ko[2 * p + 1] = kf[2 * p] * sn + kf[2 * p + 1] * c;
    }
    const float ATT = 0.08838834764831845f;  // 1/sqrt(128) folded into q
#pragma unroll
    for (int i = 0; i < 8; i++) qo[i] *= ATT;

    const int hist = 2048 - oclp[0];
    if (s < hist) {
        const float hv = hks[h];
        const float scl = 1.0f + 9.0f / (1.0f + expf(-hv));
#pragma unroll
        for (int i = 0; i < 8; i++) ko[i] *= scl;
    }

    u16x8 qo8, ko8;
#pragma unroll
    for (int i = 0; i < 8; i++) { qo8[i] = f2h(qo[i]); ko8[i] = f2h(ko[i]); }
    *(u16x8*)(q + base) = qo8;
    *(u16x8*)(k + base) = ko8;
}

// ---------------------------------------------------------------------------
// Flash attention (non-causal), S=2048, D=128. Per block: 128 q-rows, 8 waves
// of 16 rows. K-tile=64. K staged [kpos][d] pitch 136, V transposed [d][kpos]
// pitch 72, P per-wave [16][72]. LDS = 54272 B -> 2 blocks/CU.
// ---------------------------------------------------------------------------
__global__ __launch_bounds__(512) void flash_attn(
    const u16* __restrict__ Q, const u16* __restrict__ K, const u16* __restrict__ V,
    u16* __restrict__ O)
{
    const int qt = blockIdx.x;        // 0..15
    const int bh = blockIdx.y;        // 0..31
    const int b = bh >> 4, h = bh & 15;
    const int tid = threadIdx.x, l = tid & 63, w = tid >> 6;
    const int quad = l >> 4, lan = l & 15;

    __shared__ __attribute__((aligned(16))) u16 Kb[64 * 136];
    __shared__ __attribute__((aligned(16))) u16 VT[128 * 72];
    __shared__ __attribute__((aligned(16))) u16 Pb[8][16 * 72];

    f16x8 qf[4];
    {
        const int qrow = qt * 128 + w * 16 + lan;
        const u16* qp = Q + ((size_t)(b * 2048 + qrow)) * 2048 + h * 128 + quad * 8;
#pragma unroll
        for (int ks = 0; ks < 4; ks++)
            qf[ks] = __builtin_bit_cast(f16x8, *(const u16x8*)(qp + ks * 32));
    }

    float mr[4], lr[4];
    f32x4 o[8] = {};
#pragma unroll
    for (int r = 0; r < 4; r++) { mr[r] = -3.0e38f; lr[r] = 0.f; }

    for (int kt = 0; kt < 32; kt++) {
        const size_t krowbase = ((size_t)(b * 2048 + kt * 64)) * 2048 + h * 128;
        __syncthreads();
#pragma unroll
        for (int i = 0; i < 2; i++) {
            const int c = tid + 512 * i;
            const int kp = c >> 4, dc = (c & 15) * 8;
            u16x8 kv = *(const u16x8*)(K + krowbase + (size_t)kp * 2048 + dc);
            *(u16x8*)(&Kb[kp * 136 + dc]) = kv;
            const int kp2 = c & 63, dc2 = c >> 6;
            u16x8 vv = *(const u16x8*)(V + krowbase + (size_t)kp2 * 2048 + dc2 * 8);
#pragma unroll
            for (int j = 0; j < 8; j++) VT[(dc2 * 8 + j) * 72 + kp2] = vv[j];
        }
        __syncthreads();

        // S = Q K^T  (16 x 64 per wave)
        f32x4 sfr[4] = {};
#pragma unroll
        for (int ks = 0; ks < 4; ks++) {
#pragma unroll
            for (int nt = 0; nt < 4; nt++) {
                f16x8 kb = __builtin_bit_cast(f16x8,
                    *(const u16x8*)(&Kb[(nt * 16 + lan) * 136 + ks * 32 + quad * 8]));
                sfr[nt] = __builtin_amdgcn_mfma_f32_16x16x32_f16(qf[ks], kb, sfr[nt], 0, 0, 0);
            }
        }

        // online softmax; S row = quad*4 + r, cols spread over lan x nt
        float tm[4];
#pragma unroll
        for (int r = 0; r < 4; r++)
            tm[r] = fmaxf(fmaxf(sfr[0][r], sfr[1][r]), fmaxf(sfr[2][r], sfr[3][r]));
#pragma unroll
        for (int mask = 1; mask <= 8; mask <<= 1)
#pragma unroll
            for (int r = 0; r < 4; r++) tm[r] = fmaxf(tm[r], __shfl_xor(tm[r], mask));

        float al[4], rs[4];
#pragma unroll
        for (int r = 0; r < 4; r++) {
            const float mn = fmaxf(mr[r], tm[r]);
            al[r] = exp2f((mr[r] - mn) * LOG2E);
            mr[r] = mn;
            rs[r] = 0.f;
        }
#pragma unroll
        for (int nt = 0; nt < 4; nt++) {
#pragma unroll
            for (int r = 0; r < 4; r++) {
                const float p = exp2f((sfr[nt][r] - mr[r]) * LOG2E);
                rs[r] += p;
                Pb[w][(quad * 4 + r) * 72 + nt * 16 + lan] = f2h(p);
            }
        }
#pragma unroll
        for (int mask = 1; mask <= 8; mask <<= 1)
#pragma unroll
            for (int r = 0; r < 4; r++) rs[r] += __shfl_xor(rs[r], mask);
#pragma unroll
        for (int r = 0; r < 4; r++) lr[r] = lr[r] * al[r] + rs[r];
#pragma unroll
        for (int nd = 0; nd < 8; nd++)
#pragma unroll
            for (int r = 0; r < 4; r++) o[nd][r] *= al[r];

        __asm__ volatile("s_waitcnt lgkmcnt(0)" ::: "memory");

        // O += P @ V  (P A-operand from Pb; V^T B-operand from VT)
#pragma unroll
        for (int ks = 0; ks < 2; ks++) {
            f16x8 pf = __builtin_bit_cast(f16x8,
                *(const u16x8*)(&Pb[w][lan * 72 + ks * 32 + quad * 8]));
#pragma unroll
            for (int nd = 0; nd < 8; nd++) {
                f16x8 vtf = __builtin_bit_cast(f16x8,
                    *(const u16x8*)(&VT[(nd * 16 + lan) * 72 + ks * 32 + quad * 8]));
                o[nd] = __builtin_amdgcn_mfma_f32_16x16x32_f16(pf, vtf, o[nd], 0, 0, 0);
            }
        }
    }

#pragma unroll
    for (int nd = 0; nd < 8; nd++) {
#pragma unroll
        for (int r = 0; r < 4; r++) {
            const int srow = qt * 128 + w * 16 + quad * 4 + r;
            const int col = nd * 16 + lan;
            O[((size_t)(b * 2048 + srow)) * 2048 + h * 128 + col] = f2h(o[nd][r] / lr[r]);
        }
    }
}

// ---------------------------------------------------------------------------
extern "C" void kernel_launch(void* const* d_in, const int* in_sizes, int n_in,
                              void* d_out, int out_size, void* d_ws, size_t ws_size,
                              hipStream_t stream) {
    const float* hs  = (const float*)d_in[0];
    const float* rot = (const float*)d_in[1];
    const float* Wq  = (const float*)d_in[2];
    const float* bq  = (const float*)d_in[3];
    const float* Wk  = (const float*)d_in[4];
    const float* bk  = (const float*)d_in[5];
    const float* Wv  = (const float*)d_in[6];
    const float* bv  = (const float*)d_in[7];
    const float* nqw = (const float*)d_in[8];
    const float* nkw = (const float*)d_in[9];
    const float* hks = (const float*)d_in[10];
    const float* Wo  = (const float*)d_in[11];
    const float* bo  = (const float*)d_in[12];
    const int*   ocl = (const int*)d_in[13];

    u16* qraw = (u16*)d_ws;            // 4x 4096*2048 f16 = 64 MB total
    u16* kraw = qraw + 8388608;
    u16* vraw = kraw + 8388608;
    u16* aout = vraw + 8388608;
    float* out = (float*)d_out;

    // 1) QKV projection (z selects q/k/v), fp32 in -> f16 out
    gemm_bt<float, u16><<<dim3(16, 32, 3), 256, 0, stream>>>(
        hs, Wq, Wk, Wv, bq, bk, bv, qraw, 4096, 2048, 2048);
    // 2) rmsnorm + rope + history scale (in place, f16)
    norm_rope<<<dim3(4096), 256, 0, stream>>>(qraw, kraw, rot, nqw, nkw, hks, ocl);
    // 3) flash attention -> aout[b, s, h*d] (f16)
    flash_attn<<<dim3(16, 32), 512, 0, stream>>>(qraw, kraw, vraw, aout);
    // 4) output projection, f16 in -> fp32 out
    gemm_bt<u16, float><<<dim3(16, 32, 1), 256, 0, stream>>>(
        aout, Wo, Wo, Wo, bo, bo, bo, out, 4096, 2048, 2048);
}